// Round 10
// baseline (496.456 us; speedup 1.0000x reference)
//
#include <hip/hip_runtime.h>

#define MDIM 4096
#define KDIM 4096
#define NDIM 11008
#define NGROUPS 32

#define BM 128
#define BN 128
#define BK 64
#define NT (KDIM / BK)   // 64 K-tiles
#define KB (KDIM * 2)    // row stride in bytes (8192)

typedef _Float16 f16x8 __attribute__((ext_vector_type(8)));
typedef float f32x4 __attribute__((ext_vector_type(4)));

typedef const unsigned int __attribute__((address_space(1))) *gas_t;
typedef unsigned int __attribute__((address_space(3))) *las_t;

__device__ __forceinline__ void gld_lds16(const void *g, void *l) {
  __builtin_amdgcn_global_load_lds((gas_t)g, (las_t)l, 16, 0, 0);
}

// Raw barrier with memory clobber (no implicit vm/lgkm drain).
#define BAR() asm volatile("s_barrier" ::: "memory")
#define VMW4() asm volatile("s_waitcnt vmcnt(4)" ::: "memory")
#define VMW2() asm volatile("s_waitcnt vmcnt(2)" ::: "memory")
#define VMW0() asm volatile("s_waitcnt vmcnt(0)" ::: "memory")
#define FENCE() __builtin_amdgcn_sched_barrier(0)

// ---------------- prepass: A fp32 -> f16 (split kernels measured faster
// than fused: R7 ~52us vs R8 ~63us; prepass is at its memory roofline) ------
__global__ __launch_bounds__(256) void cvt_a_kernel(const float *__restrict__ a,
                                                    _Float16 *__restrict__ o) {
  const int n8 = (MDIM * KDIM) / 8;
  for (int i = blockIdx.x * blockDim.x + threadIdx.x; i < n8;
       i += gridDim.x * blockDim.x) {
    const float4 v0 = *(const float4 *)(a + (size_t)i * 8);
    const float4 v1 = *(const float4 *)(a + (size_t)i * 8 + 4);
    f16x8 h;
    h[0] = (_Float16)v0.x; h[1] = (_Float16)v0.y;
    h[2] = (_Float16)v0.z; h[3] = (_Float16)v0.w;
    h[4] = (_Float16)v1.x; h[5] = (_Float16)v1.y;
    h[6] = (_Float16)v1.z; h[7] = (_Float16)v1.w;
    *(f16x8 *)(o + (size_t)i * 8) = h;
  }
}

// ---------------- prepass: W int32 -> f16 * scale ----------------
__global__ __launch_bounds__(256) void cvt_w_kernel(const int *__restrict__ w,
                                                    const float *__restrict__ s,
                                                    _Float16 *__restrict__ o) {
  const int n8 = (NDIM * KDIM) / 8;
  for (int i = blockIdx.x * blockDim.x + threadIdx.x; i < n8;
       i += gridDim.x * blockDim.x) {
    const size_t base = (size_t)i * 8;
    const int row = (int)(base >> 12);             // /KDIM
    const int g = ((int)(base & (KDIM - 1))) >> 7; // /GROUPSIZE
    const float sc = s[row * NGROUPS + g];
    const int4 w0 = *(const int4 *)(w + base);
    const int4 w1 = *(const int4 *)(w + base + 4);
    f16x8 h;
    h[0] = (_Float16)((float)w0.x * sc); h[1] = (_Float16)((float)w0.y * sc);
    h[2] = (_Float16)((float)w0.z * sc); h[3] = (_Float16)((float)w0.w * sc);
    h[4] = (_Float16)((float)w1.x * sc); h[5] = (_Float16)((float)w1.y * sc);
    h[6] = (_Float16)((float)w1.z * sc); h[7] = (_Float16)((float)w1.w * sc);
    *(f16x8 *)(o + base) = h;
  }
}

// ---------------- main GEMM: 128x128 tile, BK=64, 8 waves, 2 blocks/CU -----
// R8 schedule isomorphically shrunk to 128x128 so LDS = 80KB -> TWO blocks
// co-resident per CU (4 waves/SIMD instead of 2). Per-CU traffic identical
// to the 256^2 champion (2x blocks x half-size): isolates occupancy.
// Wave tile 64x32 (2 wm x 4 wn). Fragments: af[4 mi][2 ks], bf[2 nj][2 ks];
// 16 MFMA/tile/wave. Phase axis = ks (no B-parity needed; each register
// group is reloaded once per tile in the phase where it's dead):
//   top: stage B(t+2)->bS
//   P1: read bf-ks1 (2) | 4 MFMA ks0 (mi0-1)
//   P2: read af-ks1 (4) | 4 MFMA ks0 (mi2-3)
//   mid: vmcnt(2) (retires B(t+1),A(t+1); keeps B(t+2)); BAR
//   P3: read af-ks0-next (4, from An) | 4 MFMA ks1 (mi0-1)
//   P4: read bf-ks0-next (2, from Bn); stage A(t+2)->aC | 4 MFMA ks1 (mi2-3)
// Ledger (isomorphic to R8, re-verified t=0/steady/NT-2/NT-1):
//  * bS holds B(t-1); its last reads (ks1, tile t-1 P1) end before tile
//    t-1's mid-BAR -> safe to stage at tile-t top.
//  * aC holds A(t); last reads P2 pre-BAR -> safe to stage at P4 post-BAR.
//  * A(t+1) issued at tile-(t-1) P4 -> ~1 tile old at this tile's vmcnt(2).
//  * prologue order A0,B0,B1,A1 + VMW4 -> in-flight [B1 2, A1 2] at t=0.
// LDS XOR-swizzle (16B involution): phys_koff = koff ^ ((row&7)*16), applied
// to the pre-swizzled staging source AND the ds_read address.
__global__ __launch_bounds__(512, 4) void gemm_8phase(
    const _Float16 *__restrict__ Ah, const _Float16 *__restrict__ Wh,
    float *__restrict__ C) {
  // [0,32KB): A slots 0,1 (16KB each); [32KB,80KB): B slots 0,1,2 (16KB).
  __shared__ __align__(16) char Sh[81920];

  const int tid = threadIdx.x;
  const int l = tid & 63;
  const int w = tid >> 6;   // wave 0..7
  const int wm = w >> 2;    // 0..1 (M half: 64 rows)
  const int wn = w & 3;     // 0..3 (N quarter: 32 cols)

  // XCD-aware bijective swizzle: 2752 blocks, 344 per XCD.
  const int wg = blockIdx.x;
  const int swz = (wg & 7) * 344 + (wg >> 3);
  const int bx = swz / 32;   // N tile 0..85
  const int by = swz % 32;   // M tile 0..31

  // staging source (pre-swizzled per lane); wave w covers rows w*8+srow
  // (+64 for the second call of each stage).
  const int srow = l >> 3;
  const int gk = ((l & 7) ^ srow) * 16;
  const char *Ag =
      (const char *)Ah + (size_t)(by * BM + w * 8 + srow) * KB + gk;
  const char *Bg =
      (const char *)Wh + (size_t)(bx * BN + w * 8 + srow) * KB + gk;

  // fragment-read offsets (bytes); row stride 128B (64 f16)
  const int laneRow = (l & 15) * 128;
  const int kx0 = ((l >> 4) * 16) ^ ((l & 7) * 16);
  const int kx1 = kx0 ^ 64;

  f32x4 acc[4][2] = {};
  f16x8 af[4][2], bf[2][2];   // [mi][ks], [nj][ks]

  // rotating LDS slot offsets (bytes into Sh)
  unsigned aC = 0, aN = 16384;
  unsigned bC = 32768, bN = 49152, bS = 65536;

  // 2-call stage: 16KB tile = 2 x (8 waves x 1KB)
#define STAGE_A(KT, OFF)                                                      \
  {                                                                           \
    const char *ap_ = Ag + (size_t)(KT) * (BK * 2);                           \
    gld_lds16(ap_, (void *)(Sh + (OFF) + w * 1024));                          \
    gld_lds16(ap_ + (size_t)64 * KB, (void *)(Sh + (OFF) + 8192 + w * 1024)); \
  }

#define STAGE_B(KT, OFF)                                                      \
  {                                                                           \
    const char *bp_ = Bg + (size_t)(KT) * (BK * 2);                           \
    gld_lds16(bp_, (void *)(Sh + (OFF) + w * 1024));                          \
    gld_lds16(bp_ + (size_t)64 * KB, (void *)(Sh + (OFF) + 8192 + w * 1024)); \
  }

#define RDA(MI, KS, BASE)                                                     \
  af[MI][KS] = *(const f16x8 *)((BASE) + wm * 8192 + (MI) * 2048 + laneRow +  \
                                ((KS) ? kx1 : kx0));

#define RDB(NJ, KS, BASE)                                                     \
  bf[NJ][KS] = *(const f16x8 *)((BASE) + wn * 4096 + (NJ) * 2048 + laneRow +  \
                                ((KS) ? kx1 : kx0));

  // 4-MFMA cluster: k-step KS, M-frags MI0..MI0+1, both nj
#define MMA4(KS, MI0)                                                         \
  __builtin_amdgcn_s_setprio(1);                                              \
  _Pragma("unroll") for (int mi = (MI0); mi < (MI0) + 2; ++mi)                \
      _Pragma("unroll") for (int nj = 0; nj < 2; ++nj)                        \
          acc[mi][nj] = __builtin_amdgcn_mfma_f32_16x16x32_f16(               \
              af[mi][KS], bf[nj][KS], acc[mi][nj], 0, 0, 0);                  \
  __builtin_amdgcn_s_setprio(0);

  // prologue. vmcnt order: A0,B0 (oldest 4, retired by VMW4), B1, A1.
  STAGE_A(0, aC);
  STAGE_B(0, bC);
  STAGE_B(1, bN);
  STAGE_A(1, aN);
  VMW4();
  BAR();
  {
    const char *A0 = (const char *)Sh + aC;
    const char *B0 = (const char *)Sh + bC;
    RDA(0, 0, A0); RDA(1, 0, A0); RDA(2, 0, A0); RDA(3, 0, A0);
    RDB(0, 0, B0); RDB(1, 0, B0);
  }

  for (int t = 0; t < NT; ++t) {
    const bool s1 = (t + 1 < NT);
    const bool s2 = (t + 2 < NT);
    const char *Ac = (const char *)Sh + aC;
    const char *An = (const char *)Sh + aN;
    const char *Bc = (const char *)Sh + bC;
    const char *Bn = (const char *)Sh + bN;

    // top: stage B(t+2) -> bS (holds B(t-1); reads ended pre prev mid-BAR)
    if (s2) { STAGE_B(t + 2, bS); }

    // P1: read bf-ks1 | MFMA ks0 (mi0-1)
    RDB(0, 1, Bc);
    RDB(1, 1, Bc);
    FENCE(); MMA4(0, 0);

    // P2: read af-ks1 | MFMA ks0 (mi2-3)
    RDA(0, 1, Ac); RDA(1, 1, Ac);
    FENCE(); MMA4(0, 2);
    RDA(2, 1, Ac); RDA(3, 1, Ac);
    FENCE();

    // mid: counted retire + publish. In-flight oldest-first:
    // [B(t+1) 2, A(t+1) 2, B(t+2) 2] -> vmcnt(2) retires B(t+1),A(t+1).
    if (s2) { VMW2(); } else { VMW0(); }
    BAR();

    // P3: read af-ks0-next (An published) | MFMA ks1 (mi0-1)
    if (s1) { RDA(0, 0, An); RDA(1, 0, An); }
    FENCE(); MMA4(1, 0);
    if (s1) { RDA(2, 0, An); RDA(3, 0, An); }
    FENCE();

    // P4: read bf-ks0-next + stage A(t+2)->aC | MFMA ks1 (mi2-3)
    if (s1) { RDB(0, 0, Bn); RDB(1, 0, Bn); }
    FENCE(); MMA4(1, 2);
    if (s2) { STAGE_A(t + 2, aC); }

    // rotate LDS slots
    { const unsigned ta = aC; aC = aN; aN = ta; }
    { const unsigned tb = bC; bC = bN; bN = bS; bS = tb; }
  }

#undef STAGE_A
#undef STAGE_B
#undef RDA
#undef RDB
#undef MMA4

  // C/D layout: col = lane&15, row = (lane>>4)*4 + reg
  const int fr = l & 15, fq = l >> 4;
  float *Cb = C + (size_t)(by * BM + wm * 64) * NDIM + bx * BN + wn * 32;
#pragma unroll
  for (int i = 0; i < 4; ++i)
#pragma unroll
    for (int j = 0; j < 2; ++j)
#pragma unroll
      for (int r = 0; r < 4; ++r)
        Cb[(size_t)(i * 16 + fq * 4 + r) * NDIM + j * 16 + fr] = acc[i][j][r];
}

// ---------------- fallback: fused dequant GEMM (no workspace needed) -------
__global__ __launch_bounds__(256) void gemm_fused(const float *__restrict__ A,
                                                  const int *__restrict__ W,
                                                  const float *__restrict__ S,
                                                  float *__restrict__ C) {
  __shared__ _Float16 Asf[128 * 64];
  __shared__ _Float16 Bsf[128 * 64];
  const int tid = threadIdx.x;
  const int lane = tid & 63;
  const int wv = tid >> 6;
  const int wm = wv >> 1, wn = wv & 1;
  const int bx = blockIdx.x, by = blockIdx.y;
  const int srow = tid >> 1;
  const int skof = (tid & 1) * 32;

  const float *Ab = A + (size_t)(by * 128 + srow) * KDIM + skof;
  const int *Wb = W + (size_t)(bx * 128 + srow) * KDIM + skof;
  const float *Sb = S + (size_t)(bx * 128 + srow) * NGROUPS;

  f32x4 acc[4][4] = {};
  float4 ar[8];
  int4 wr[8];
  float sc;

#pragma unroll
  for (int u = 0; u < 8; ++u) {
    ar[u] = *(const float4 *)(Ab + u * 4);
    wr[u] = *(const int4 *)(Wb + u * 4);
  }
  sc = Sb[0];

  const int fr = lane & 15;
  const int fq = lane >> 4;
  const int kbase = fq * 8;

  for (int kt = 0; kt < KDIM / 64; ++kt) {
    __syncthreads();
    _Float16 *Ad = &Asf[srow * 64 + skof];
    _Float16 *Bd = &Bsf[srow * 64 + skof];
#pragma unroll
    for (int u = 0; u < 4; ++u) {
      const float4 a0 = ar[2 * u], a1 = ar[2 * u + 1];
      const int4 b0 = wr[2 * u], b1 = wr[2 * u + 1];
      f16x8 ha, hb;
      ha[0] = (_Float16)a0.x; ha[1] = (_Float16)a0.y;
      ha[2] = (_Float16)a0.z; ha[3] = (_Float16)a0.w;
      ha[4] = (_Float16)a1.x; ha[5] = (_Float16)a1.y;
      ha[6] = (_Float16)a1.z; ha[7] = (_Float16)a1.w;
      hb[0] = (_Float16)((float)b0.x * sc); hb[1] = (_Float16)((float)b0.y * sc);
      hb[2] = (_Float16)((float)b0.z * sc); hb[3] = (_Float16)((float)b0.w * sc);
      hb[4] = (_Float16)((float)b1.x * sc); hb[5] = (_Float16)((float)b1.y * sc);
      hb[6] = (_Float16)((float)b1.z * sc); hb[7] = (_Float16)((float)b1.w * sc);
      *(f16x8 *)(Ad + u * 8) = ha;
      *(f16x8 *)(Bd + u * 8) = hb;
    }
    if (kt + 1 < KDIM / 64) {
      const float *An = Ab + (kt + 1) * 64;
      const int *Wn = Wb + (kt + 1) * 64;
#pragma unroll
      for (int u = 0; u < 8; ++u) {
        ar[u] = *(const float4 *)(An + u * 4);
        wr[u] = *(const int4 *)(Wn + u * 4);
      }
      sc = Sb[(kt + 1) >> 1];
    }
    __syncthreads();
#pragma unroll
    for (int ks = 0; ks < 2; ++ks) {
      f16x8 afv[4], bfv[4];
      const int kof = ks * 32 + kbase;
#pragma unroll
      for (int i = 0; i < 4; ++i) {
        afv[i] = *(const f16x8 *)&Asf[(wm * 64 + i * 16 + fr) * 64 + kof];
        bfv[i] = *(const f16x8 *)&Bsf[(wn * 64 + i * 16 + fr) * 64 + kof];
      }
#pragma unroll
      for (int i = 0; i < 4; ++i)
#pragma unroll
        for (int j = 0; j < 4; ++j)
          acc[i][j] = __builtin_amdgcn_mfma_f32_16x16x32_f16(afv[i], bfv[j],
                                                             acc[i][j], 0, 0, 0);
    }
  }

  float *Cb = C + (size_t)(by * 128 + wm * 64) * NDIM + bx * 128 + wn * 64;
#pragma unroll
  for (int i = 0; i < 4; ++i)
#pragma unroll
    for (int j = 0; j < 4; ++j)
#pragma unroll
      for (int r = 0; r < 4; ++r)
        Cb[(size_t)(i * 16 + fq * 4 + r) * NDIM + j * 16 + fr] = acc[i][j][r];
}

extern "C" void kernel_launch(void *const *d_in, const int *in_sizes, int n_in,
                              void *d_out, int out_size, void *d_ws,
                              size_t ws_size, hipStream_t stream) {
  (void)in_sizes; (void)n_in; (void)out_size;
  const float *A = (const float *)d_in[0];
  const int *W = (const int *)d_in[1];
  const float *S = (const float *)d_in[2];
  float *C = (float *)d_out;

  const size_t needA = (size_t)MDIM * KDIM * sizeof(_Float16);
  const size_t needW = (size_t)NDIM * KDIM * sizeof(_Float16);

  if (ws_size >= needA + needW) {
    _Float16 *Ahp = (_Float16 *)d_ws;
    _Float16 *Whp = (_Float16 *)((char *)d_ws + needA);
    cvt_a_kernel<<<2048, 256, 0, stream>>>(A, Ahp);
    cvt_w_kernel<<<2048, 256, 0, stream>>>(W, S, Whp);
    gemm_8phase<<<(MDIM / BM) * (NDIM / BN), 512, 0, stream>>>(Ahp, Whp, C);
  } else {
    dim3 grid(NDIM / 128, MDIM / 128);
    gemm_fused<<<grid, 256, 0, stream>>>(A, W, S, C);
  }
}